// Round 20
// baseline (184.282 us; speedup 1.0000x reference)
//
#include <hip/hip_runtime.h>
#include <hip/hip_bf16.h>
#include <math.h>

typedef unsigned short u16;
typedef __attribute__((ext_vector_type(8))) __bf16 bf16x8;
typedef __attribute__((ext_vector_type(4))) float f32x4;

__device__ inline u16 f2bf(float f) {
  union { float f; unsigned u; } x; x.f = f;
  unsigned r = x.u + 0x7fffu + ((x.u >> 16) & 1u);
  return (u16)(r >> 16);
}

__device__ inline float bf2f(u16 h) {
  union { unsigned u; float f; } x; x.u = ((unsigned)h) << 16;
  return x.f;
}

__device__ inline unsigned cvtpk(float lo, float hi) {
  unsigned r;
  asm("v_cvt_pk_bf16_f32 %0, %1, %2" : "=v"(r) : "v"(lo), "v"(hi));
  return r;
}

__device__ inline float fexp2(float x) {
  float r;
  asm("v_exp_f32 %0, %1" : "=v"(r) : "v"(x));
  return r;
}

__device__ inline void async16(const void* g, void* l) {
  __builtin_amdgcn_global_load_lds(
      (const __attribute__((address_space(1))) void*)g,
      (__attribute__((address_space(3))) void*)l, 16, 0, 0);
}

// ------------- fused cast f32 -> bf16, 32B/lane (hs | attn_w | proj_w) -----
__global__ __launch_bounds__(256) void cast3_kernel(
    const float* __restrict__ hs, const float* __restrict__ aw,
    const float* __restrict__ pw, u16* __restrict__ hs_o,
    u16* __restrict__ aw_o, u16* __restrict__ pw_o) {
  int blk = blockIdx.x;
  const float* in;
  u16* out;
  int i;
  if (blk < 4096) {
    in = hs; out = hs_o; i = blk * 256 + threadIdx.x;
  } else if (blk < 6400) {
    in = aw; out = aw_o; i = (blk - 4096) * 256 + threadIdx.x;
  } else {
    in = pw; out = pw_o; i = (blk - 6400) * 256 + threadIdx.x;
  }
#pragma unroll
  for (int p = 0; p < 2; ++p) {
    int q = i * 2 + p;
    float4 v = ((const float4*)in)[q];
    u16 o0 = f2bf(v.x), o1 = f2bf(v.y), o2 = f2bf(v.z), o3 = f2bf(v.w);
    unsigned lo = (unsigned)o0 | ((unsigned)o1 << 16);
    unsigned hi = (unsigned)o2 | ((unsigned)o3 << 16);
    ((uint2*)out)[q] = make_uint2(lo, hi);
  }
}

// ---------------- GEMM: C[M][N] = A[M][K] * W[N][K]^T + bias ----------------
// r19 proven: dbuf BK=64, one __syncthreads per K-step, XCD chunk swizzle,
// per-lane LDS read bases; V-panel blocks also store acc transposed to vtout.
template <bool BF16OUT>
__global__ __launch_bounds__(256) void gemm_bt(
    const u16* __restrict__ A, const u16* __restrict__ Bw,
    const float* __restrict__ bias, void* __restrict__ Cout,
    u16* __restrict__ vtout, int M, int N, int K, int qcols, float qscale) {
  __shared__ u16 As[2][128 * 64];
  __shared__ u16 Bs[2][128 * 64];
  const int t = threadIdx.x;
  const int w = t >> 6;
  const int lane = t & 63;
  const int lq = lane >> 4, lr = lane & 15;

  int bx = blockIdx.x, by = blockIdx.y;
  const int gx = gridDim.x, gy = gridDim.y;
  if ((gx & 1) == 0 && (gy & 3) == 0) {
    const int cw = gx >> 1, ch = gy >> 2;
    int id = by * gx + bx;
    int xcd = id & 7, j = id >> 3;
    bx = (xcd & 1) * cw + j % cw;
    by = (xcd >> 1) * ch + j / cw;
  }

  const long brow = (long)by * 128;
  const long bcol = (long)bx * 128;
  const int wr = (w >> 1) * 64, wc = (w & 1) * 64;
  f32x4 acc[4][4] = {};

  int rA[4], cA[4];
#pragma unroll
  for (int it = 0; it < 4; ++it) {
    int ci = it * 256 + t;
    rA[it] = ci >> 3;
    cA[it] = (ci & 7) ^ (rA[it] & 7);
  }

  char* const AsB = (char*)&As[0][0];
  char* const BsB = (char*)&Bs[0][0];

  auto stage = [&](int buf, int kt) {
    char* ad = AsB + buf * 16384;
    char* bd = BsB + buf * 16384;
#pragma unroll
    for (int it = 0; it < 4; ++it) {
      const u16* srcA = A + (brow + rA[it]) * (long)K + kt + cA[it] * 8;
      async16(srcA, ad + (it * 256 + w * 64) * 16);
      const u16* srcB = Bw + (bcol + rA[it]) * (long)K + kt + cA[it] * 8;
      async16(srcB, bd + (it * 256 + w * 64) * 16);
    }
  };

  const int swz = ((lr & 4) << 4) + ((lq << 4) ^ ((lr & 3) << 4));
  const int aB0 = (wr + lr) * 128 + swz;
  const int bB0 = (wc + lr) * 128 + swz;
  const char* const a00 = AsB + aB0;
  const char* const a01 = AsB + (aB0 ^ 64);
  const char* const a10 = AsB + 16384 + aB0;
  const char* const a11 = AsB + 16384 + (aB0 ^ 64);
  const char* const b00 = BsB + bB0;
  const char* const b01 = BsB + (bB0 ^ 64);
  const char* const b10 = BsB + 16384 + bB0;
  const char* const b11 = BsB + 16384 + (bB0 ^ 64);

  auto computeK = [&](const char* a0, const char* a1, const char* b0,
                      const char* b1) {
    bf16x8 af[4], bfr[4];
#pragma unroll
    for (int m = 0; m < 4; ++m) af[m] = *(const bf16x8*)(a0 + m * 2048);
#pragma unroll
    for (int n = 0; n < 4; ++n) bfr[n] = *(const bf16x8*)(b0 + n * 2048);
#pragma unroll
    for (int m = 0; m < 4; ++m)
#pragma unroll
      for (int n = 0; n < 4; ++n)
        acc[m][n] = __builtin_amdgcn_mfma_f32_16x16x32_bf16(
            af[m], bfr[n], acc[m][n], 0, 0, 0);
#pragma unroll
    for (int m = 0; m < 4; ++m) af[m] = *(const bf16x8*)(a1 + m * 2048);
#pragma unroll
    for (int n = 0; n < 4; ++n) bfr[n] = *(const bf16x8*)(b1 + n * 2048);
#pragma unroll
    for (int m = 0; m < 4; ++m)
#pragma unroll
      for (int n = 0; n < 4; ++n)
        acc[m][n] = __builtin_amdgcn_mfma_f32_16x16x32_bf16(
            af[m], bfr[n], acc[m][n], 0, 0, 0);
  };

  stage(0, 0);
  __syncthreads();

  for (int kt = 0; kt < K; kt += 128) {
    if (kt + 64 < K) stage(1, kt + 64);
    computeK(a00, a01, b00, b01);
    __syncthreads();
    if (kt + 128 < K) stage(0, kt + 128);
    computeK(a10, a11, b10, b11);
    __syncthreads();
  }

#pragma unroll
  for (int m = 0; m < 4; ++m) {
    long row0 = brow + wr + m * 16 + lq * 4;
#pragma unroll
    for (int n = 0; n < 4; ++n) {
      long col = bcol + wc + n * 16 + lr;
      float bv = bias[col];
      float cs = (col < qcols) ? qscale : 1.f;
#pragma unroll
      for (int j = 0; j < 4; ++j) {
        float v = (acc[m][n][j] + bv) * cs;
        if (BF16OUT)
          ((u16*)Cout)[(row0 + j) * N + col] = f2bf(v);
        else
          ((float*)Cout)[(row0 + j) * N + col] = v;
      }
    }
  }

  // fused V-transpose: this block's cols are the V panel (d = col-2176)
  if (BF16OUT && vtout != nullptr && bcol == 2176) {
    const int bb = (int)(brow >> 11);
    const int s0 = (int)(brow & 2047) + wr + lq * 4;
#pragma unroll
    for (int m = 0; m < 4; ++m)
#pragma unroll
      for (int n = 0; n < 4; ++n) {
        int d = wc + n * 16 + lr;
        float bv = bias[2176 + d];
        union { u16 h[4]; uint2 u; } pk;
#pragma unroll
        for (int j = 0; j < 4; ++j) pk.h[j] = f2bf(acc[m][n][j] + bv);
        *(uint2*)(vtout + ((size_t)bb * 128 + d) * 2048 + s0 + m * 16) = pk.u;
      }
  }
}

// ---------------- Flash attention (MQA, causal) — split-KV ----------------
// Light blocks (qt<8): r19 path, write ctx directly. Heavy blocks (qt>=8):
// split into 2 KV-half pieces (512 pieces dispatched first, heaviest first);
// each writes UNNORMALIZED o (bf16 [128][128]) + per-row m,l to pws; a
// combine kernel merges. Shortens the longest serial chain 32 -> 17 tiles.
__global__ __launch_bounds__(256, 2) void attn_kernel(
    const u16* __restrict__ qkv, const u16* __restrict__ vt,
    u16* __restrict__ ctx, u16* __restrict__ pws) {
  __shared__ u16 Kl[2][64 * 136];  // 272B stride, 17408B per buffer
  __shared__ u16 Vl[2][128 * 72];  // 144B stride, 18432B per buffer

  const int t = threadIdx.x;
  const int w = t >> 6;
  const int lane = t & 63;
  const int lq = lane >> 4, lr = lane & 15;
  const int lkey = lq * 4;
  const int kbase8 = lq << 3;
  const int bid = blockIdx.x;

  int qt, j0, j1, hb;
  bool split;
  if (bid < 512) {  // heavy pieces, heaviest first
    int u = bid >> 6;
    int half = (bid >> 5) & 1;
    hb = bid & 31;
    qt = 15 - u;
    int T = 2 * qt + 2, T0 = T >> 1;
    j0 = half ? T0 : 0;
    j1 = half ? T : T0;
    split = true;
  } else {
    int u2 = (bid - 512) >> 5;
    hb = bid & 31;
    qt = 7 - u2;
    j0 = 0;
    j1 = 2 * qt + 2;
    split = false;
  }
  const int h = hb & 15;
  const int b = hb >> 4;
  const int s0w = qt * 128 + w * 32;
  const size_t qb = (size_t)b * 2048 * 2304;

  bf16x8 qg[2][4];
#pragma unroll
  for (int s = 0; s < 2; ++s)
#pragma unroll
    for (int kc = 0; kc < 4; ++kc)
      qg[s][kc] = *(const bf16x8*)(qkv + qb +
                                   (size_t)(s0w + s * 16 + lr) * 2304 +
                                   h * 128 + kc * 32 + lq * 8);

  const u16* kp[5];
  const u16* vp[5];
#pragma unroll
  for (int ii = 0; ii < 5; ++ii) {
    int I = 4 * ii + w;
    {
      int pp = I * 1024 + lane * 16;
      int row = pp / 272;
      int rem = pp - row * 272;
      int ch = (rem < 256) ? (rem >> 4) : 0;
      if (row > 63) row = 63;
      int g = row >> 4, lqr = row & 15;
      int key = ((g & 1) << 5) + ((lqr >> 2) << 3) + ((g >> 1) << 2) +
                (lqr & 3);
      kp[ii] = qkv + qb + (size_t)(key + j0 * 64) * 2304 + 2048 + ch * 8;
    }
    {
      int pp = I * 1024 + lane * 16;
      int row = pp / 144;
      int rem = pp - row * 144;
      int ch = (rem < 128) ? (rem >> 4) : 0;
      if (row > 127) row = 127;
      vp[ii] = vt + ((size_t)b * 128 + row) * 2048 + j0 * 64 + ch * 8;
    }
  }
  char* const KlB = (char*)&Kl[0][0];
  char* const VlB = (char*)&Vl[0][0];

  auto stage = [&](int buf) {
    char* kd = KlB + buf * 17408;
    char* vd = VlB + buf * 18432;
#pragma unroll
    for (int ii = 0; ii < 5; ++ii) {
      int I = 4 * ii + w;
      if (I < 17) {
        async16(kp[ii], kd + I * 1024);
        kp[ii] += 64 * 2304;
      }
    }
#pragma unroll
    for (int ii = 0; ii < 5; ++ii) {
      int I = 4 * ii + w;
      if (I < 18) {
        async16(vp[ii], vd + I * 1024);
        vp[ii] += 64;
      }
    }
  };

  const int loK = lr * 272 + lq * 16;
  const int loV = lr * 144 + lq * 16;

  float mreg[2] = {-INFINITY, -INFINITY};
  float lreg[2] = {0.f, 0.f};
  f32x4 o[2][8] = {};

  stage(0);
  __syncthreads();

  int cur = 0;
  for (int j2 = j0; j2 < j1; ++j2) {
    const int kvb = j2 * 64;
    if (j2 + 1 < j1) stage(cur ^ 1);
    if (kvb <= s0w + 31) {
      const char* KL = KlB + cur * 17408 + loK;
      const char* VL = VlB + cur * 18432 + loV;
      const bool maskT = (kvb + 63 > s0w);

      f32x4 sc[2][4] = {};
#pragma unroll
      for (int g = 0; g < 4; ++g)
#pragma unroll
        for (int kc = 0; kc < 4; ++kc) {
          bf16x8 kf = *(const bf16x8*)(KL + g * 4352 + kc * 64);
          sc[0][g] = __builtin_amdgcn_mfma_f32_16x16x32_bf16(kf, qg[0][kc],
                                                             sc[0][g], 0, 0, 0);
          sc[1][g] = __builtin_amdgcn_mfma_f32_16x16x32_bf16(kf, qg[1][kc],
                                                             sc[1][g], 0, 0, 0);
        }

      bf16x8 vf[16];
#pragma unroll
      for (int n = 0; n < 8; ++n) {
        vf[2 * n] = *(const bf16x8*)(VL + n * 2304);
        vf[2 * n + 1] = *(const bf16x8*)(VL + n * 2304 + 64);
      }

#pragma unroll
      for (int s = 0; s < 2; ++s) {
        float vv[16];
#pragma unroll
        for (int uu = 0; uu < 16; ++uu) vv[uu] = sc[s][uu >> 2][uu & 3];
        if (maskT) {
          const int qrel = s0w + s * 16 + lr - kvb - kbase8;
#pragma unroll
          for (int g = 0; g < 4; ++g)
#pragma unroll
            for (int r = 0; r < 4; ++r)
              if (((g & 1) << 5) + ((g >> 1) << 2) + r > qrel)
                vv[g * 4 + r] = -INFINITY;
        }
        float mx = vv[0];
#pragma unroll
        for (int uu = 1; uu < 16; ++uu) mx = fmaxf(mx, vv[uu]);
        mx = fmaxf(mx, __shfl_xor(mx, 16));
        mx = fmaxf(mx, __shfl_xor(mx, 32));
        float mn = mreg[s];
        if (__any(mx > mn + 8.f)) {  // T13 defer-rescale
          float mu = fmaxf(mn, mx);
          float alpha = fexp2(mn - mu);
          mreg[s] = mu;
          mn = mu;
          lreg[s] *= alpha;
          float a0 = __shfl(alpha, lkey + 0);
          float a1 = __shfl(alpha, lkey + 1);
          float a2 = __shfl(alpha, lkey + 2);
          float a3 = __shfl(alpha, lkey + 3);
#pragma unroll
          for (int n = 0; n < 8; ++n) {
            o[s][n][0] *= a0;
            o[s][n][1] *= a1;
            o[s][n][2] *= a2;
            o[s][n][3] *= a3;
          }
        }
        float e[16];
        float rs = 0.f;
#pragma unroll
        for (int uu = 0; uu < 16; ++uu) {
          e[uu] = fexp2(vv[uu] - mn);
          rs += e[uu];
        }
        lreg[s] += rs;
        bf16x8 pa0, pa1;
        {
          union { unsigned uw[4]; bf16x8 v; } pk;
          pk.uw[0] = cvtpk(e[0], e[1]);
          pk.uw[1] = cvtpk(e[2], e[3]);
          pk.uw[2] = cvtpk(e[8], e[9]);
          pk.uw[3] = cvtpk(e[10], e[11]);
          pa0 = pk.v;
          pk.uw[0] = cvtpk(e[4], e[5]);
          pk.uw[1] = cvtpk(e[6], e[7]);
          pk.uw[2] = cvtpk(e[12], e[13]);
          pk.uw[3] = cvtpk(e[14], e[15]);
          pa1 = pk.v;
        }
#pragma unroll
        for (int n = 0; n < 8; ++n) {
          o[s][n] = __builtin_amdgcn_mfma_f32_16x16x32_bf16(pa0, vf[2 * n],
                                                            o[s][n], 0, 0, 0);
          o[s][n] = __builtin_amdgcn_mfma_f32_16x16x32_bf16(pa1, vf[2 * n + 1],
                                                            o[s][n], 0, 0, 0);
        }
      }
    }
    __syncthreads();
    cur ^= 1;
  }

  if (split) {
    // partial store: o unnormalized bf16 [128][128] + per-row m,l (f32)
    u16* const po = pws + (size_t)bid * 16896;
    float* const pml = (float*)(po + 16384);
#pragma unroll
    for (int s = 0; s < 2; ++s) {
      float lsum = lreg[s];
      lsum += __shfl_xor(lsum, 16);
      lsum += __shfl_xor(lsum, 32);
      if (lq == 0) {
        pml[w * 32 + s * 16 + lr] = mreg[s];
        pml[128 + w * 32 + s * 16 + lr] = lsum;
      }
#pragma unroll
      for (int r = 0; r < 4; ++r) {
        int row = w * 32 + s * 16 + lkey + r;
#pragma unroll
        for (int n = 0; n < 8; ++n)
          po[row * 128 + n * 16 + lr] = f2bf(o[s][n][r]);
      }
    }
  } else {
#pragma unroll
    for (int s = 0; s < 2; ++s) {
      float lsum = lreg[s];
      lsum += __shfl_xor(lsum, 16);
      lsum += __shfl_xor(lsum, 32);
      float inv = 1.f / lsum;
      float iv[4];
      iv[0] = __shfl(inv, lkey + 0);
      iv[1] = __shfl(inv, lkey + 1);
      iv[2] = __shfl(inv, lkey + 2);
      iv[3] = __shfl(inv, lkey + 3);
#pragma unroll
      for (int r = 0; r < 4; ++r) {
        size_t rowoff =
            ((size_t)b * 2048 + s0w + s * 16 + lkey + r) * 2048 + h * 128;
#pragma unroll
        for (int n = 0; n < 8; ++n)
          ctx[rowoff + n * 16 + lr] = f2bf(o[s][n][r] * iv[r]);
      }
    }
  }
}

// ---------------- split-KV combine: ctx = merge(piece0, piece1) ------------
__global__ __launch_bounds__(256) void combine_kernel(
    const u16* __restrict__ pws, u16* __restrict__ ctx) {
  const int bid = blockIdx.x;
  const int u = bid >> 5, hb = bid & 31;
  const int h = hb & 15, b = hb >> 4;
  const int qt = 15 - u;
  const u16* const p0 = pws + (size_t)(u * 64 + hb) * 16896;
  const u16* const p1 = pws + (size_t)(u * 64 + 32 + hb) * 16896;
  const float* const ml0 = (const float*)(p0 + 16384);
  const float* const ml1 = (const float*)(p1 + 16384);

  __shared__ float f0s[128], f1s[128];
  const int t = threadIdx.x;
  if (t < 128) {
    float m0 = ml0[t], l0 = ml0[128 + t];
    float m1 = ml1[t], l1 = ml1[128 + t];
    float M = fmaxf(m0, m1);
    float w0 = fexp2(m0 - M), w1 = fexp2(m1 - M);
    float L = l0 * w0 + l1 * w1;
    f0s[t] = w0 / L;
    f1s[t] = w1 / L;
  }
  __syncthreads();

  const int row = t >> 1, dh = (t & 1) * 64;
  const float f0 = f0s[row], f1 = f1s[row];
  const uint4* r0 = (const uint4*)(p0 + row * 128 + dh);
  const uint4* r1 = (const uint4*)(p1 + row * 128 + dh);
  uint4* dst =
      (uint4*)(ctx + ((size_t)b * 2048 + qt * 128 + row) * 2048 + h * 128 + dh);
#pragma unroll
  for (int j = 0; j < 8; ++j) {
    uint4 A = r0[j], B = r1[j];
    const unsigned* pa = (const unsigned*)&A;
    const unsigned* pb = (const unsigned*)&B;
    uint4 O;
    unsigned* po = (unsigned*)&O;
#pragma unroll
    for (int k = 0; k < 4; ++k) {
      float v0 = bf2f((u16)(pa[k] & 0xffff)) * f0 +
                 bf2f((u16)(pb[k] & 0xffff)) * f1;
      float v1 = bf2f((u16)(pa[k] >> 16)) * f0 +
                 bf2f((u16)(pb[k] >> 16)) * f1;
      po[k] = (unsigned)f2bf(v0) | ((unsigned)f2bf(v1) << 16);
    }
    dst[j] = O;
  }
}

extern "C" void kernel_launch(void* const* d_in, const int* in_sizes, int n_in,
                              void* d_out, int out_size, void* d_ws,
                              size_t ws_size, hipStream_t stream) {
  (void)in_sizes; (void)n_in; (void)out_size; (void)ws_size;
  const float* hs = (const float*)d_in[0];
  const float* attn_w = (const float*)d_in[1];
  const float* attn_b = (const float*)d_in[2];
  const float* proj_w = (const float*)d_in[3];
  const float* proj_b = (const float*)d_in[4];
  float* out = (float*)d_out;

  u16* hs_b = (u16*)d_ws;                      // 4096*2048
  u16* aw_b = hs_b + (size_t)4096 * 2048;      // 2304*2048
  u16* pw_b = aw_b + (size_t)2304 * 2048;      // 2048*2048
  u16* qkv_b = pw_b + (size_t)2048 * 2048;     // 4096*2304
  u16* vt_b = qkv_b + (size_t)4096 * 2304;     // 2*128*2048
  u16* ctx_b = vt_b + (size_t)2 * 128 * 2048;  // 4096*2048
  u16* pws = ctx_b + (size_t)4096 * 2048;      // 512*16896 (17.3MB)

  const float qscale = 0.08838834764831845f * 1.4426950408889634f;

  cast3_kernel<<<8448, 256, 0, stream>>>(hs, attn_w, proj_w, hs_b, aw_b,
                                         pw_b);

  gemm_bt<true><<<dim3(18, 32), 256, 0, stream>>>(hs_b, aw_b, attn_b, qkv_b,
                                                  vt_b, 4096, 2304, 2048,
                                                  2048, qscale);
  attn_kernel<<<768, 256, 0, stream>>>(qkv_b, vt_b, ctx_b, pws);
  combine_kernel<<<256, 256, 0, stream>>>(pws, ctx_b);
  gemm_bt<false><<<dim3(16, 32), 256, 0, stream>>>(ctx_b, pw_b, proj_b, out,
                                                   nullptr, 4096, 2048, 2048,
                                                   0, 1.f);
}

// Round 21
// 172.683 us; speedup vs baseline: 1.0672x; 1.0672x over previous
//
#include <hip/hip_runtime.h>
#include <hip/hip_bf16.h>
#include <math.h>

typedef unsigned short u16;
typedef __attribute__((ext_vector_type(8))) __bf16 bf16x8;
typedef __attribute__((ext_vector_type(4))) float f32x4;

__device__ inline u16 f2bf(float f) {
  union { float f; unsigned u; } x; x.f = f;
  unsigned r = x.u + 0x7fffu + ((x.u >> 16) & 1u);
  return (u16)(r >> 16);
}

__device__ inline unsigned cvtpk(float lo, float hi) {
  unsigned r;
  asm("v_cvt_pk_bf16_f32 %0, %1, %2" : "=v"(r) : "v"(lo), "v"(hi));
  return r;
}

__device__ inline float fexp2(float x) {
  float r;
  asm("v_exp_f32 %0, %1" : "=v"(r) : "v"(x));
  return r;
}

__device__ inline void async16(const void* g, void* l) {
  __builtin_amdgcn_global_load_lds(
      (const __attribute__((address_space(1))) void*)g,
      (__attribute__((address_space(3))) void*)l, 16, 0, 0);
}

// ------------- fused cast f32 -> bf16, 32B/lane (hs | attn_w | proj_w) -----
__global__ __launch_bounds__(256) void cast3_kernel(
    const float* __restrict__ hs, const float* __restrict__ aw,
    const float* __restrict__ pw, u16* __restrict__ hs_o,
    u16* __restrict__ aw_o, u16* __restrict__ pw_o) {
  int blk = blockIdx.x;
  const float* in;
  u16* out;
  int i;
  if (blk < 4096) {
    in = hs; out = hs_o; i = blk * 256 + threadIdx.x;
  } else if (blk < 6400) {
    in = aw; out = aw_o; i = (blk - 4096) * 256 + threadIdx.x;
  } else {
    in = pw; out = pw_o; i = (blk - 6400) * 256 + threadIdx.x;
  }
#pragma unroll
  for (int p = 0; p < 2; ++p) {
    int q = i * 2 + p;
    float4 v = ((const float4*)in)[q];
    u16 o0 = f2bf(v.x), o1 = f2bf(v.y), o2 = f2bf(v.z), o3 = f2bf(v.w);
    unsigned lo = (unsigned)o0 | ((unsigned)o1 << 16);
    unsigned hi = (unsigned)o2 | ((unsigned)o3 << 16);
    ((uint2*)out)[q] = make_uint2(lo, hi);
  }
}

// ---------------- GEMM: C[M][N] = A[M][K] * W[N][K]^T + bias ----------------
// dbuf BK=64, one __syncthreads per K-step, XCD chunk swizzle, precomputed
// per-lane LDS read bases; V-panel blocks also store acc transposed to vtout.
template <bool BF16OUT>
__global__ __launch_bounds__(256) void gemm_bt(
    const u16* __restrict__ A, const u16* __restrict__ Bw,
    const float* __restrict__ bias, void* __restrict__ Cout,
    u16* __restrict__ vtout, int M, int N, int K, int qcols, float qscale) {
  __shared__ u16 As[2][128 * 64];
  __shared__ u16 Bs[2][128 * 64];
  const int t = threadIdx.x;
  const int w = t >> 6;
  const int lane = t & 63;
  const int lq = lane >> 4, lr = lane & 15;

  int bx = blockIdx.x, by = blockIdx.y;
  const int gx = gridDim.x, gy = gridDim.y;
  if ((gx & 1) == 0 && (gy & 3) == 0) {
    const int cw = gx >> 1, ch = gy >> 2;
    int id = by * gx + bx;
    int xcd = id & 7, j = id >> 3;
    bx = (xcd & 1) * cw + j % cw;
    by = (xcd >> 1) * ch + j / cw;
  }

  const long brow = (long)by * 128;
  const long bcol = (long)bx * 128;
  const int wr = (w >> 1) * 64, wc = (w & 1) * 64;
  f32x4 acc[4][4] = {};

  int rA[4], cA[4];
#pragma unroll
  for (int it = 0; it < 4; ++it) {
    int ci = it * 256 + t;
    rA[it] = ci >> 3;
    cA[it] = (ci & 7) ^ (rA[it] & 7);
  }

  char* const AsB = (char*)&As[0][0];
  char* const BsB = (char*)&Bs[0][0];

  auto stage = [&](int buf, int kt) {
    char* ad = AsB + buf * 16384;
    char* bd = BsB + buf * 16384;
#pragma unroll
    for (int it = 0; it < 4; ++it) {
      const u16* srcA = A + (brow + rA[it]) * (long)K + kt + cA[it] * 8;
      async16(srcA, ad + (it * 256 + w * 64) * 16);
      const u16* srcB = Bw + (bcol + rA[it]) * (long)K + kt + cA[it] * 8;
      async16(srcB, bd + (it * 256 + w * 64) * 16);
    }
  };

  const int swz = ((lr & 4) << 4) + ((lq << 4) ^ ((lr & 3) << 4));
  const int aB0 = (wr + lr) * 128 + swz;
  const int bB0 = (wc + lr) * 128 + swz;
  const char* const a00 = AsB + aB0;
  const char* const a01 = AsB + (aB0 ^ 64);
  const char* const a10 = AsB + 16384 + aB0;
  const char* const a11 = AsB + 16384 + (aB0 ^ 64);
  const char* const b00 = BsB + bB0;
  const char* const b01 = BsB + (bB0 ^ 64);
  const char* const b10 = BsB + 16384 + bB0;
  const char* const b11 = BsB + 16384 + (bB0 ^ 64);

  auto computeK = [&](const char* a0, const char* a1, const char* b0,
                      const char* b1) {
    bf16x8 af[4], bfr[4];
#pragma unroll
    for (int m = 0; m < 4; ++m) af[m] = *(const bf16x8*)(a0 + m * 2048);
#pragma unroll
    for (int n = 0; n < 4; ++n) bfr[n] = *(const bf16x8*)(b0 + n * 2048);
#pragma unroll
    for (int m = 0; m < 4; ++m)
#pragma unroll
      for (int n = 0; n < 4; ++n)
        acc[m][n] = __builtin_amdgcn_mfma_f32_16x16x32_bf16(
            af[m], bfr[n], acc[m][n], 0, 0, 0);
#pragma unroll
    for (int m = 0; m < 4; ++m) af[m] = *(const bf16x8*)(a1 + m * 2048);
#pragma unroll
    for (int n = 0; n < 4; ++n) bfr[n] = *(const bf16x8*)(b1 + n * 2048);
#pragma unroll
    for (int m = 0; m < 4; ++m)
#pragma unroll
      for (int n = 0; n < 4; ++n)
        acc[m][n] = __builtin_amdgcn_mfma_f32_16x16x32_bf16(
            af[m], bfr[n], acc[m][n], 0, 0, 0);
  };

  stage(0, 0);
  __syncthreads();

  for (int kt = 0; kt < K; kt += 128) {
    if (kt + 64 < K) stage(1, kt + 64);
    computeK(a00, a01, b00, b01);
    __syncthreads();
    if (kt + 128 < K) stage(0, kt + 128);
    computeK(a10, a11, b10, b11);
    __syncthreads();
  }

#pragma unroll
  for (int m = 0; m < 4; ++m) {
    long row0 = brow + wr + m * 16 + lq * 4;
#pragma unroll
    for (int n = 0; n < 4; ++n) {
      long col = bcol + wc + n * 16 + lr;
      float bv = bias[col];
      float cs = (col < qcols) ? qscale : 1.f;
#pragma unroll
      for (int j = 0; j < 4; ++j) {
        float v = (acc[m][n][j] + bv) * cs;
        if (BF16OUT)
          ((u16*)Cout)[(row0 + j) * N + col] = f2bf(v);
        else
          ((float*)Cout)[(row0 + j) * N + col] = v;
      }
    }
  }

  // fused V-transpose: this block's cols are the V panel (d = col-2176)
  if (BF16OUT && vtout != nullptr && bcol == 2176) {
    const int bb = (int)(brow >> 11);
    const int s0 = (int)(brow & 2047) + wr + lq * 4;
#pragma unroll
    for (int m = 0; m < 4; ++m)
#pragma unroll
      for (int n = 0; n < 4; ++n) {
        int d = wc + n * 16 + lr;
        float bv = bias[2176 + d];
        union { u16 h[4]; uint2 u; } pk;
#pragma unroll
        for (int j = 0; j < 4; ++j) pk.h[j] = f2bf(acc[m][n][j] + bv);
        *(uint2*)(vtout + ((size_t)bb * 128 + d) * 2048 + s0 + m * 16) = pk.u;
      }
  }
}

// ---------------- Flash attention (MQA, causal) ----------------
// r18 proven version (65.5us): kappa-permuted K rows -> in-register P via
// cvt_pk (no Pl); V preload after QK^T; per-half softmax->PV interleave;
// per-lane l partials reduced once in the epilogue; heavy-first order.
__global__ __launch_bounds__(256, 2) void attn_kernel(
    const u16* __restrict__ qkv, const u16* __restrict__ vt,
    u16* __restrict__ ctx) {
  __shared__ u16 Kl[2][64 * 136];  // 272B stride, 17408B per buffer
  __shared__ u16 Vl[2][128 * 72];  // 144B stride, 18432B per buffer

  const int t = threadIdx.x;
  const int w = t >> 6;
  const int lane = t & 63;
  const int lq = lane >> 4, lr = lane & 15;
  const int lkey = lq * 4;
  const int kbase8 = lq << 3;
  const int bid = blockIdx.x;
  const int qtid = bid >> 5;
  const int qt = (qtid < 8) ? (15 - qtid) : (qtid - 8);  // heavy first
  const int hb = bid & 31;
  const int h = hb & 15;
  const int b = hb >> 4;
  const int s0w = qt * 128 + w * 32;
  const size_t qb = (size_t)b * 2048 * 2304;

  bf16x8 qg[2][4];
#pragma unroll
  for (int s = 0; s < 2; ++s)
#pragma unroll
    for (int kc = 0; kc < 4; ++kc)
      qg[s][kc] = *(const bf16x8*)(qkv + qb +
                                   (size_t)(s0w + s * 16 + lr) * 2304 +
                                   h * 128 + kc * 32 + lq * 8);

  const u16* kp[5];
  const u16* vp[5];
#pragma unroll
  for (int ii = 0; ii < 5; ++ii) {
    int I = 4 * ii + w;
    {
      int pp = I * 1024 + lane * 16;
      int row = pp / 272;
      int rem = pp - row * 272;
      int ch = (rem < 256) ? (rem >> 4) : 0;
      if (row > 63) row = 63;
      int g = row >> 4, lqr = row & 15;
      int key = ((g & 1) << 5) + ((lqr >> 2) << 3) + ((g >> 1) << 2) +
                (lqr & 3);
      kp[ii] = qkv + qb + (size_t)key * 2304 + 2048 + ch * 8;
    }
    {
      int pp = I * 1024 + lane * 16;
      int row = pp / 144;
      int rem = pp - row * 144;
      int ch = (rem < 128) ? (rem >> 4) : 0;
      if (row > 127) row = 127;
      vp[ii] = vt + ((size_t)b * 128 + row) * 2048 + ch * 8;
    }
  }
  char* const KlB = (char*)&Kl[0][0];
  char* const VlB = (char*)&Vl[0][0];

  auto stage = [&](int buf) {
    char* kd = KlB + buf * 17408;
    char* vd = VlB + buf * 18432;
#pragma unroll
    for (int ii = 0; ii < 5; ++ii) {
      int I = 4 * ii + w;
      if (I < 17) {
        async16(kp[ii], kd + I * 1024);
        kp[ii] += 64 * 2304;
      }
    }
#pragma unroll
    for (int ii = 0; ii < 5; ++ii) {
      int I = 4 * ii + w;
      if (I < 18) {
        async16(vp[ii], vd + I * 1024);
        vp[ii] += 64;
      }
    }
  };

  const int loK = lr * 272 + lq * 16;
  const int loV = lr * 144 + lq * 16;

  float mreg[2] = {-INFINITY, -INFINITY};
  float lreg[2] = {0.f, 0.f};
  f32x4 o[2][8] = {};
  const int ntiles = 2 * qt + 2;

  stage(0);
  __syncthreads();

  int cur = 0;
  for (int j2 = 0; j2 < ntiles; ++j2) {
    const int kvb = j2 * 64;
    if (j2 + 1 < ntiles) stage(cur ^ 1);
    if (kvb <= s0w + 31) {
      const char* KL = KlB + cur * 17408 + loK;
      const char* VL = VlB + cur * 18432 + loV;
      const bool maskT = (kvb + 63 > s0w);

      f32x4 sc[2][4] = {};
#pragma unroll
      for (int g = 0; g < 4; ++g)
#pragma unroll
        for (int kc = 0; kc < 4; ++kc) {
          bf16x8 kf = *(const bf16x8*)(KL + g * 4352 + kc * 64);
          sc[0][g] = __builtin_amdgcn_mfma_f32_16x16x32_bf16(kf, qg[0][kc],
                                                             sc[0][g], 0, 0, 0);
          sc[1][g] = __builtin_amdgcn_mfma_f32_16x16x32_bf16(kf, qg[1][kc],
                                                             sc[1][g], 0, 0, 0);
        }

      bf16x8 vf[16];
#pragma unroll
      for (int n = 0; n < 8; ++n) {
        vf[2 * n] = *(const bf16x8*)(VL + n * 2304);
        vf[2 * n + 1] = *(const bf16x8*)(VL + n * 2304 + 64);
      }

#pragma unroll
      for (int s = 0; s < 2; ++s) {
        float vv[16];
#pragma unroll
        for (int uu = 0; uu < 16; ++uu) vv[uu] = sc[s][uu >> 2][uu & 3];
        if (maskT) {
          const int qrel = s0w + s * 16 + lr - kvb - kbase8;
#pragma unroll
          for (int g = 0; g < 4; ++g)
#pragma unroll
            for (int r = 0; r < 4; ++r)
              if (((g & 1) << 5) + ((g >> 1) << 2) + r > qrel)
                vv[g * 4 + r] = -INFINITY;
        }
        float mx = vv[0];
#pragma unroll
        for (int uu = 1; uu < 16; ++uu) mx = fmaxf(mx, vv[uu]);
        mx = fmaxf(mx, __shfl_xor(mx, 16));
        mx = fmaxf(mx, __shfl_xor(mx, 32));
        float mn = mreg[s];
        if (__any(mx > mn + 8.f)) {  // T13 defer-rescale
          float mu = fmaxf(mn, mx);
          float alpha = fexp2(mn - mu);
          mreg[s] = mu;
          mn = mu;
          lreg[s] *= alpha;
          float a0 = __shfl(alpha, lkey + 0);
          float a1 = __shfl(alpha, lkey + 1);
          float a2 = __shfl(alpha, lkey + 2);
          float a3 = __shfl(alpha, lkey + 3);
#pragma unroll
          for (int n = 0; n < 8; ++n) {
            o[s][n][0] *= a0;
            o[s][n][1] *= a1;
            o[s][n][2] *= a2;
            o[s][n][3] *= a3;
          }
        }
        float e[16];
        float rs = 0.f;
#pragma unroll
        for (int uu = 0; uu < 16; ++uu) {
          e[uu] = fexp2(vv[uu] - mn);
          rs += e[uu];
        }
        lreg[s] += rs;
        bf16x8 pa0, pa1;
        {
          union { unsigned uw[4]; bf16x8 v; } pk;
          pk.uw[0] = cvtpk(e[0], e[1]);
          pk.uw[1] = cvtpk(e[2], e[3]);
          pk.uw[2] = cvtpk(e[8], e[9]);
          pk.uw[3] = cvtpk(e[10], e[11]);
          pa0 = pk.v;
          pk.uw[0] = cvtpk(e[4], e[5]);
          pk.uw[1] = cvtpk(e[6], e[7]);
          pk.uw[2] = cvtpk(e[12], e[13]);
          pk.uw[3] = cvtpk(e[14], e[15]);
          pa1 = pk.v;
        }
#pragma unroll
        for (int n = 0; n < 8; ++n) {
          o[s][n] = __builtin_amdgcn_mfma_f32_16x16x32_bf16(pa0, vf[2 * n],
                                                            o[s][n], 0, 0, 0);
          o[s][n] = __builtin_amdgcn_mfma_f32_16x16x32_bf16(pa1, vf[2 * n + 1],
                                                            o[s][n], 0, 0, 0);
        }
      }
    }
    __syncthreads();
    cur ^= 1;
  }

#pragma unroll
  for (int s = 0; s < 2; ++s) {
    float lsum = lreg[s];
    lsum += __shfl_xor(lsum, 16);
    lsum += __shfl_xor(lsum, 32);
    float inv = 1.f / lsum;
    float iv[4];
    iv[0] = __shfl(inv, lkey + 0);
    iv[1] = __shfl(inv, lkey + 1);
    iv[2] = __shfl(inv, lkey + 2);
    iv[3] = __shfl(inv, lkey + 3);
#pragma unroll
    for (int r = 0; r < 4; ++r) {
      size_t rowoff =
          ((size_t)b * 2048 + s0w + s * 16 + lkey + r) * 2048 + h * 128;
#pragma unroll
      for (int n = 0; n < 8; ++n)
        ctx[rowoff + n * 16 + lr] = f2bf(o[s][n][r] * iv[r]);
    }
  }
}

extern "C" void kernel_launch(void* const* d_in, const int* in_sizes, int n_in,
                              void* d_out, int out_size, void* d_ws,
                              size_t ws_size, hipStream_t stream) {
  (void)in_sizes; (void)n_in; (void)out_size; (void)ws_size;
  const float* hs = (const float*)d_in[0];
  const float* attn_w = (const float*)d_in[1];
  const float* attn_b = (const float*)d_in[2];
  const float* proj_w = (const float*)d_in[3];
  const float* proj_b = (const float*)d_in[4];
  float* out = (float*)d_out;

  u16* hs_b = (u16*)d_ws;                      // 4096*2048
  u16* aw_b = hs_b + (size_t)4096 * 2048;      // 2304*2048
  u16* pw_b = aw_b + (size_t)2304 * 2048;      // 2048*2048
  u16* qkv_b = pw_b + (size_t)2048 * 2048;     // 4096*2304
  u16* vt_b = qkv_b + (size_t)4096 * 2304;     // 2*128*2048
  u16* ctx_b = vt_b + (size_t)2 * 128 * 2048;  // 4096*2048

  const float qscale = 0.08838834764831845f * 1.4426950408889634f;

  cast3_kernel<<<8448, 256, 0, stream>>>(hs, attn_w, proj_w, hs_b, aw_b,
                                         pw_b);

  gemm_bt<true><<<dim3(18, 32), 256, 0, stream>>>(hs_b, aw_b, attn_b, qkv_b,
                                                  vt_b, 4096, 2304, 2048,
                                                  2048, qscale);
  attn_kernel<<<512, 256, 0, stream>>>(qkv_b, vt_b, ctx_b);
  gemm_bt<false><<<dim3(16, 32), 256, 0, stream>>>(ctx_b, pw_b, proj_b, out,
                                                   nullptr, 4096, 2048, 2048,
                                                   0, 1.f);
}